// Round 2
// baseline (345.744 us; speedup 1.0000x reference)
//
#include <hip/hip_runtime.h>
#include <stdint.h>

// Problem constants (fixed by setup_inputs)
#define BB 8
#define DD 32
#define HH 48
#define WW 48
#define HWSZ 2304          // 48*48
#define NROW 18432         // B*HW
#define KQ 8192
#define NCOL 8200          // 8 + 8192

// d_out offsets (floats)
#define OFF_LOGITS 0
#define OFF_TMP    151142400
#define OFF_LLOG   151160832
#define OFF_LLBL   151271424
#define OFF_SAL    151289856

// ---------------- threefry2x32 (exact JAX rounds) ----------------
__device__ __forceinline__ uint32_t rotl_d(uint32_t x, int d){ return (x<<d)|(x>>(32-d)); }

__device__ __forceinline__ void tf2x32(uint32_t k0, uint32_t k1, uint32_t x0, uint32_t x1,
                                       uint32_t &o0, uint32_t &o1){
  uint32_t ks2 = k0 ^ k1 ^ 0x1BD11BDAu;
  x0 += k0; x1 += k1;
  // group 1 (13,15,26,6)
  x0+=x1; x1=rotl_d(x1,13); x1^=x0;
  x0+=x1; x1=rotl_d(x1,15); x1^=x0;
  x0+=x1; x1=rotl_d(x1,26); x1^=x0;
  x0+=x1; x1=rotl_d(x1, 6); x1^=x0;
  x0+=k1; x1+=ks2+1u;
  // group 2 (17,29,16,24)
  x0+=x1; x1=rotl_d(x1,17); x1^=x0;
  x0+=x1; x1=rotl_d(x1,29); x1^=x0;
  x0+=x1; x1=rotl_d(x1,16); x1^=x0;
  x0+=x1; x1=rotl_d(x1,24); x1^=x0;
  x0+=ks2; x1+=k0+2u;
  // group 3 (13,15,26,6)
  x0+=x1; x1=rotl_d(x1,13); x1^=x0;
  x0+=x1; x1=rotl_d(x1,15); x1^=x0;
  x0+=x1; x1=rotl_d(x1,26); x1^=x0;
  x0+=x1; x1=rotl_d(x1, 6); x1^=x0;
  x0+=k0; x1+=k1+3u;
  // group 4 (17,29,16,24)
  x0+=x1; x1=rotl_d(x1,17); x1^=x0;
  x0+=x1; x1=rotl_d(x1,29); x1^=x0;
  x0+=x1; x1=rotl_d(x1,16); x1^=x0;
  x0+=x1; x1=rotl_d(x1,24); x1^=x0;
  x0+=k1; x1+=ks2+4u;
  // group 5 (13,15,26,6)
  x0+=x1; x1=rotl_d(x1,13); x1^=x0;
  x0+=x1; x1=rotl_d(x1,15); x1^=x0;
  x0+=x1; x1=rotl_d(x1,26); x1^=x0;
  x0+=x1; x1=rotl_d(x1, 6); x1^=x0;
  x0+=ks2; x1+=k0+5u;
  o0=x0; o1=x1;
}

static inline uint32_t rotl_h(uint32_t x,int d){return (x<<d)|(x>>(32-d));}
static void tf_host(uint32_t k0,uint32_t k1,uint32_t x0,uint32_t x1,uint32_t&o0,uint32_t&o1){
  uint32_t ks2=k0^k1^0x1BD11BDAu;
  x0+=k0;x1+=k1;
  const int RA[4]={13,15,26,6}, RBR[4]={17,29,16,24};
  for(int i=0;i<4;++i){x0+=x1;x1=rotl_h(x1,RA[i]);x1^=x0;}
  x0+=k1; x1+=ks2+1u;
  for(int i=0;i<4;++i){x0+=x1;x1=rotl_h(x1,RBR[i]);x1^=x0;}
  x0+=ks2; x1+=k0+2u;
  for(int i=0;i<4;++i){x0+=x1;x1=rotl_h(x1,RA[i]);x1^=x0;}
  x0+=k0; x1+=k1+3u;
  for(int i=0;i<4;++i){x0+=x1;x1=rotl_h(x1,RBR[i]);x1^=x0;}
  x0+=k1; x1+=ks2+4u;
  for(int i=0;i<4;++i){x0+=x1;x1=rotl_h(x1,RA[i]);x1^=x0;}
  x0+=ks2; x1+=k0+5u;
  o0=x0;o1=x1;
}

// ---------------- kernels ----------------

// normalize q over D; write q_flat[row*32+d], row = b*HW+hw. 4 waves/block, 1 row/wave.
__global__ __launch_bounds__(256) void k_qnorm(const float* __restrict__ q, float* __restrict__ q_flat){
  int wave = threadIdx.x>>6, lane = threadIdx.x&63;
  int row = blockIdx.x*4 + wave;
  int b = row/HWSZ, hw = row%HWSZ;
  float v = 0.f;
  if (lane < 32) v = q[((size_t)(b*DD+lane))*HWSZ + hw];
  float ss = v*v;
  ss += __shfl_xor(ss,16,64); ss+=__shfl_xor(ss,8,64); ss+=__shfl_xor(ss,4,64);
  ss+=__shfl_xor(ss,2,64); ss+=__shfl_xor(ss,1,64);
  float inv = 1.f / fmaxf(sqrtf(ss), 1e-12f);
  if (lane < 32) q_flat[(size_t)row*DD + lane] = v * inv;
}

// w[b,hw] = sal_k / max(||k_feat[b,:,hw]||, 1e-12)
__global__ __launch_bounds__(256) void k_wk(const float* __restrict__ kf, const float* __restrict__ sal_k,
                                            float* __restrict__ w){
  int wave = threadIdx.x>>6, lane = threadIdx.x&63;
  int row = blockIdx.x*4 + wave;
  int b = row/HWSZ, hw = row%HWSZ;
  float v = 0.f;
  if (lane < 32) v = kf[((size_t)(b*DD+lane))*HWSZ + hw];
  float ss = v*v;
  ss += __shfl_xor(ss,16,64); ss+=__shfl_xor(ss,8,64); ss+=__shfl_xor(ss,4,64);
  ss+=__shfl_xor(ss,2,64); ss+=__shfl_xor(ss,1,64);
  if (lane == 0) w[row] = sal_k[row] * (1.f / fmaxf(sqrtf(ss), 1e-12f));
}

// protos_raw[b*32+d] = sum_hw kf[b,d,hw]*w[b,hw]
__global__ __launch_bounds__(256) void k_protos(const float* __restrict__ kf, const float* __restrict__ w,
                                                float* __restrict__ praw){
  int bd = blockIdx.x;
  int b = bd >> 5;
  const float* src = kf + (size_t)bd*HWSZ;
  const float* wp  = w + (size_t)b*HWSZ;
  float s = 0.f;
  for (int i = threadIdx.x; i < HWSZ; i += 256) s += src[i]*wp[i];
  s += __shfl_xor(s,32,64); s+=__shfl_xor(s,16,64); s+=__shfl_xor(s,8,64);
  s+=__shfl_xor(s,4,64); s+=__shfl_xor(s,2,64); s+=__shfl_xor(s,1,64);
  __shared__ float red[4];
  int wave = threadIdx.x>>6, lane = threadIdx.x&63;
  if (lane==0) red[wave]=s;
  __syncthreads();
  if (threadIdx.x==0) praw[bd] = red[0]+red[1]+red[2]+red[3];
}

// normalize protos over d (32-lane groups within one 256-thread block)
__global__ __launch_bounds__(256) void k_pnorm(const float* __restrict__ praw, float* __restrict__ pn){
  int t = threadIdx.x;
  float v = praw[t];
  float ss = v*v;
  ss += __shfl_xor(ss,16,64); ss+=__shfl_xor(ss,8,64); ss+=__shfl_xor(ss,4,64);
  ss+=__shfl_xor(ss,2,64); ss+=__shfl_xor(ss,1,64);
  pn[t] = v / fmaxf(sqrtf(ss), 1e-12f);
}

// per-column inverse norm of queue (32 x 8192)
__global__ __launch_bounds__(256) void k_qn(const float* __restrict__ queue, float* __restrict__ iqn){
  int j = blockIdx.x*256 + threadIdx.x;
  float ss = 0.f;
#pragma unroll
  for (int d=0; d<DD; ++d){ float v = queue[(size_t)d*KQ + j]; ss += v*v; }
  iqn[j] = 1.f / fmaxf(sqrtf(ss), 1e-12f);
}

// tmp, l_labels, balanced-BCE partial sums
__global__ __launch_bounds__(256) void k_sal(const float* __restrict__ q_bg, const float* __restrict__ sal_q,
                                             float* __restrict__ tmp_out, float* __restrict__ lbl_out,
                                             float* __restrict__ acc){
  int i = blockIdx.x*256 + threadIdx.x;  // 72*256 = 18432 exactly
  float s = sal_q[i];
  int b = i / HWSZ;
  float tmpv = (s + 2.f*(float)b) * s;
  tmp_out[i] = floorf(tmpv * 0.5f);
  lbl_out[i] = 0.f;
  float x = q_bg[i];
  float c = log1pf(expf(-fabsf(x)));
  float sp_neg = fmaxf(-x,0.f) + c;   // softplus(-x)
  float sp_pos = fmaxf( x,0.f) + c;   // softplus(x)
  float loss = sp_neg*s + sp_pos*(1.f - s);
  float a0 = s, a1 = s*loss, a2 = (1.f-s)*loss;
  a0+=__shfl_xor(a0,32,64); a1+=__shfl_xor(a1,32,64); a2+=__shfl_xor(a2,32,64);
  a0+=__shfl_xor(a0,16,64); a1+=__shfl_xor(a1,16,64); a2+=__shfl_xor(a2,16,64);
  a0+=__shfl_xor(a0, 8,64); a1+=__shfl_xor(a1, 8,64); a2+=__shfl_xor(a2, 8,64);
  a0+=__shfl_xor(a0, 4,64); a1+=__shfl_xor(a1, 4,64); a2+=__shfl_xor(a2, 4,64);
  a0+=__shfl_xor(a0, 2,64); a1+=__shfl_xor(a1, 2,64); a2+=__shfl_xor(a2, 2,64);
  a0+=__shfl_xor(a0, 1,64); a1+=__shfl_xor(a1, 1,64); a2+=__shfl_xor(a2, 1,64);
  if ((threadIdx.x&63)==0){ atomicAdd(&acc[0],a0); atomicAdd(&acc[1],a1); atomicAdd(&acc[2],a2); }
}

__global__ void k_fin(const float* __restrict__ acc, float* __restrict__ out_sal){
  float numel = (float)NROW;
  float npos = acc[0];
  float nneg = numel - npos;
  out_sal[0] = (nneg/numel*acc[1] + npos/numel*acc[2]) / numel;
}

// direction gumbel argmax (partitionable threefry: bits = o0^o1 of tf(key,0,i))
// + positive dot -> l_logits[:,0]
__global__ __launch_bounds__(256) void k_dirpos(const float* __restrict__ q_flat, float* __restrict__ llog,
                                                uint32_t kd0, uint32_t kd1){
  int wave = threadIdx.x>>6, lane = threadIdx.x&63;
  int row = blockIdx.x*4 + wave;
  int b = row/HWSZ, hw = row%HWSZ;
  int r = hw/WW, c = hw%WW;
  uint32_t m = 0;
  if (lane < 4){
    uint32_t i = (uint32_t)row*4u + (uint32_t)lane;   // flat index into (B,H,W,4)
    uint32_t o0,o1;
    tf2x32(kd0,kd1,0u,i,o0,o1);
    m = (o0 ^ o1) >> 9;
  }
  uint32_t mm[4];
  mm[0]=__shfl(m,0,64); mm[1]=__shfl(m,1,64); mm[2]=__shfl(m,2,64); mm[3]=__shfl(m,3,64);
  const int sr[4]={1,-1,0,0}, sc[4]={0,0,1,-1};
  int best=-1; uint32_t bb=0;
#pragma unroll
  for (int j=0;j<4;++j){
    int nr=r+sr[j], nc=c+sc[j];
    bool ok = (nr>=0)&&(nr<HH)&&(nc>=0)&&(nc<WW);
    if (ok && (best<0 || mm[j]>bb)){ best=j; bb=mm[j]; }
  }
  int pos = (r+sr[best])*WW + (c+sc[best]);
  int prow = b*HWSZ + pos;
  float a=0.f, v=0.f;
  if (lane<32){ a=q_flat[(size_t)row*DD+lane]; v=q_flat[(size_t)prow*DD+lane]; }
  float d = a*v;
  d+=__shfl_xor(d,16,64); d+=__shfl_xor(d,8,64); d+=__shfl_xor(d,4,64);
  d+=__shfl_xor(d,2,64); d+=__shfl_xor(d,1,64);
  if (lane==0) llog[(size_t)row*6] = 2.f*d;
}

// top-5 gumbel negatives per row (partitionable bits) + dots -> l_logits[:,1..5]
__global__ __launch_bounds__(256) void k_neg(const float* __restrict__ q_flat, float* __restrict__ llog,
                                             uint32_t kn0, uint32_t kn1){
  int wave = threadIdx.x>>6, lane = threadIdx.x&63;
  int row = blockIdx.x*4 + wave;     // b*HW + h
  int b = row/HWSZ, h = row%HWSZ;
  uint32_t base = (uint32_t)row * (uint32_t)HWSZ;
  uint64_t t0=0,t1=0,t2=0,t3=0,t4=0;
#pragma unroll 4
  for (int it=0; it<36; ++it){
    int c = lane + (it<<6);
    uint32_t i = base + (uint32_t)c;   // flat index into (B,HW,HW)
    uint32_t o0,o1;
    tf2x32(kn0,kn1,0u,i,o0,o1);
    if (c == h) continue;   // diagonal = -inf
    uint32_t m = (o0 ^ o1) >> 9; // float mantissa bits: equal m == equal gumbel
    uint64_t key = ((uint64_t)m << 12) | (uint64_t)(2303 - c);  // ties -> lower index wins
    if (key > t4){
      if      (key > t0){ t4=t3;t3=t2;t2=t1;t1=t0;t0=key; }
      else if (key > t1){ t4=t3;t3=t2;t2=t1;t1=key; }
      else if (key > t2){ t4=t3;t3=t2;t2=key; }
      else if (key > t3){ t4=t3;t3=key; }
      else t4=key;
    }
  }
  int idx[5];
#pragma unroll
  for (int k=0;k<5;++k){
    unsigned long long bk = (t0<<6) | (unsigned long long)lane;
    #pragma unroll
    for (int o=1;o<64;o<<=1){
      unsigned long long other = __shfl_xor(bk,o,64);
      if (other > bk) bk = other;
    }
    int wl = (int)(bk & 63ull);
    idx[k] = 2303 - (int)((bk >> 6) & 0xFFFull);
    if (lane == wl){ t0=t1; t1=t2; t2=t3; t3=t4; t4=0; }
  }
  float qv = 0.f;
  if (lane < 32) qv = q_flat[(size_t)row*DD + lane];
#pragma unroll
  for (int k=0;k<5;++k){
    float nv = 0.f;
    if (lane < 32) nv = q_flat[(size_t)(b*HWSZ + idx[k])*DD + lane];
    float d = qv*nv;
    d+=__shfl_xor(d,16,64); d+=__shfl_xor(d,8,64); d+=__shfl_xor(d,4,64);
    d+=__shfl_xor(d,2,64); d+=__shfl_xor(d,1,64);
    if (lane==0) llog[(size_t)row*6 + 1 + k] = 2.f*d;
  }
}

// logits[:, 0:8] = 2 * q_flat @ protos_n^T
__global__ __launch_bounds__(256) void k_lbatch(const float* __restrict__ q_flat, const float* __restrict__ pn,
                                                float* __restrict__ out){
  __shared__ float p[256];
  p[threadIdx.x] = pn[threadIdx.x];
  __syncthreads();
  int row = blockIdx.x*256 + threadIdx.x;
  const float4* q4 = (const float4*)(q_flat + (size_t)row*DD);
  float4 qv[8];
#pragma unroll
  for (int i=0;i<8;++i) qv[i]=q4[i];
  float res[8];
#pragma unroll
  for (int pb=0; pb<8; ++pb){
    const float* pp = &p[pb*32];
    float s = 0.f;
#pragma unroll
    for (int i=0;i<8;++i)
      s += qv[i].x*pp[i*4+0] + qv[i].y*pp[i*4+1] + qv[i].z*pp[i*4+2] + qv[i].w*pp[i*4+3];
    res[pb]=s;
  }
  float4* o4 = (float4*)(out + (size_t)row*NCOL);
  o4[0] = make_float4(2.f*res[0],2.f*res[1],2.f*res[2],2.f*res[3]);
  o4[1] = make_float4(2.f*res[4],2.f*res[5],2.f*res[6],2.f*res[7]);
}

// logits[:, 8:8200] = 2 * q_flat @ queue_n ; tile = 32 rows x 512 cols, 2 cols/thread
__global__ __launch_bounds__(256) void k_lmem(const float* __restrict__ q_flat, const float* __restrict__ queue,
                                              const float* __restrict__ iqn, float* __restrict__ out){
  __shared__ float qs[32*32];
  int t = threadIdx.x;
  int r0 = blockIdx.y * 32;
  int j0 = blockIdx.x * 512;
  ((float4*)qs)[t] = ((const float4*)(q_flat + (size_t)r0*DD))[t];
  __syncthreads();
  int ja = j0 + t, jb = j0 + 256 + t;
  float qa[32], qb[32];
  float ia = iqn[ja], ib = iqn[jb];
#pragma unroll
  for (int d=0; d<32; ++d){
    qa[d] = queue[(size_t)d*KQ + ja] * ia;
    qb[d] = queue[(size_t)d*KQ + jb] * ib;
  }
#pragma unroll 4
  for (int r=0; r<32; ++r){
    float sa=0.f, sb=0.f;
#pragma unroll
    for (int d4=0; d4<8; ++d4){
      float4 q = *(const float4*)&qs[r*32 + d4*4];
      sa += q.x*qa[d4*4+0]; sb += q.x*qb[d4*4+0];
      sa += q.y*qa[d4*4+1]; sb += q.y*qb[d4*4+1];
      sa += q.z*qa[d4*4+2]; sb += q.z*qb[d4*4+2];
      sa += q.w*qa[d4*4+3]; sb += q.w*qb[d4*4+3];
    }
    float* orow = out + (size_t)(r0+r)*NCOL + 8;
    orow[ja] = 2.f*sa;
    orow[jb] = 2.f*sb;
  }
}

extern "C" void kernel_launch(void* const* d_in, const int* in_sizes, int n_in,
                              void* d_out, int out_size, void* d_ws, size_t ws_size,
                              hipStream_t stream) {
  const float* q_feat = (const float*)d_in[0];
  const float* k_feat = (const float*)d_in[1];
  const float* q_bg   = (const float*)d_in[2];
  const float* sal_q  = (const float*)d_in[3];
  const float* sal_k  = (const float*)d_in[4];
  const float* queue  = (const float*)d_in[5];
  (void)in_sizes; (void)n_in; (void)out_size; (void)ws_size;

  float* out    = (float*)d_out;
  float* logits = out + OFF_LOGITS;
  float* tmp    = out + OFF_TMP;
  float* llog   = out + OFF_LLOG;
  float* llbl   = out + OFF_LLBL;
  float* sal    = out + OFF_SAL;

  float* ws     = (float*)d_ws;
  float* q_flat = ws;                  // 589824
  float* wk     = ws + 589824;         // 18432
  float* praw   = ws + 608256;         // 256
  float* pn     = ws + 608512;         // 256
  float* iqn    = ws + 608768;         // 8192
  float* acc    = ws + 616960;         // 3

  // JAX partitionable (threefry_partitionable=True, default since 0.4.30):
  // split(key(42)) fold-like: keys[i] = threefry2x32((0,42), hi=0, lo=i)
  uint32_t kd0,kd1,kn0,kn1;
  tf_host(0u,42u,0u,0u,kd0,kd1);   // k_dir
  tf_host(0u,42u,0u,1u,kn0,kn1);   // k_neg

  hipMemsetAsync(acc, 0, 3*sizeof(float), stream);

  k_qnorm <<<NROW/4, 256, 0, stream>>>(q_feat, q_flat);
  k_wk    <<<NROW/4, 256, 0, stream>>>(k_feat, sal_k, wk);
  k_protos<<<256,    256, 0, stream>>>(k_feat, wk, praw);
  k_pnorm <<<1,      256, 0, stream>>>(praw, pn);
  k_qn    <<<KQ/256, 256, 0, stream>>>(queue, iqn);
  k_sal   <<<NROW/256,256,0, stream>>>(q_bg, sal_q, tmp, llbl, acc);
  k_fin   <<<1,      1,   0, stream>>>(acc, sal);
  k_dirpos<<<NROW/4, 256, 0, stream>>>(q_flat, llog, kd0, kd1);
  k_neg   <<<NROW/4, 256, 0, stream>>>(q_flat, llog, kn0, kn1);
  k_lbatch<<<NROW/256,256,0, stream>>>(q_flat, pn, logits);
  k_lmem  <<<dim3(KQ/512, NROW/32), 256, 0, stream>>>(q_flat, queue, iqn, logits);
}